// Round 11
// baseline (568.343 us; speedup 1.0000x reference)
//
#include <hip/hip_runtime.h>
#include <hip/hip_bf16.h>

#define NE 8
#define NT 512
#define DIN 7168
#define DINT 2048
#define BK 64

typedef __bf16 bf16x8 __attribute__((ext_vector_type(8)));
typedef float f32x4 __attribute__((ext_vector_type(4)));
typedef unsigned short ushort8v __attribute__((ext_vector_type(8)));

#define MFMA __builtin_amdgcn_mfma_f32_16x16x32_bf16

// XOR swizzle (T2): 16B granule within a 128B row XOR'd with row&7.
__device__ __forceinline__ int swz(int row, int k) {
    return (row << 6) + (((k >> 3) ^ (row & 7)) << 3) + (k & 7);
}

__device__ __forceinline__ unsigned short b16(float f) {
    return __builtin_bit_cast(unsigned short, (__bf16)f);
}
__device__ __forceinline__ ushort8v cvt8(float4 a, float4 b) {
    ushort8v h;
    h[0] = b16(a.x); h[1] = b16(a.y); h[2] = b16(a.z); h[3] = b16(a.w);
    h[4] = b16(b.x); h[5] = b16(b.y); h[6] = b16(b.z); h[7] = b16(b.w);
    return h;
}
__device__ __forceinline__ ushort4 cvt4(float4 v) {
    ushort4 h;
    h.x = b16(v.x); h.y = b16(v.y); h.z = b16(v.z); h.w = b16(v.w);
    return h;
}

// lgkm-only drain + raw barrier (T4: vmcnt stays in flight)
__device__ __forceinline__ void barrier_lgkm() {
    asm volatile("s_waitcnt lgkmcnt(0)" ::: "memory");
    __builtin_amdgcn_s_barrier();
}

// ---------------- Kernel A: gate+up, producer/consumer ----------------
// 768 thr = 12 waves. Waves 0-7: consumers (pure ds_read+MFMA; 64x64 wave
// tile, dual acc). Waves 8-11: producers (all VMEM+cvt+ds_write; pw0/1 = x
// halves, pw2 = w1, pw3 = w3; 32 loads + 16 writes each per tile). dbuf
// 128 KB LDS, ONE s_barrier per tile, vmcnt never drained.
// grid (16,2,8) = 256 blocks = 1/CU, 1 round (FETCH-clean).
__global__ __launch_bounds__(768, 3) void ffn_gate_up(
    const float* __restrict__ x, const float* __restrict__ w1,
    const float* __restrict__ b1, const float* __restrict__ w3,
    const float* __restrict__ b3, unsigned short* __restrict__ g) {
    __shared__ unsigned short As[2][256 * BK];   // 2x32 KB
    __shared__ unsigned short B1s[2][128 * BK];  // 2x16 KB
    __shared__ unsigned short B3s[2][128 * BK];  // 2x16 KB

    const int tid = threadIdx.x;
    const int lane = tid & 63;
    const int wave = tid >> 6;  // 0..11
    const int e = blockIdx.z;
    const int bn = blockIdx.x * 128;
    const int bm = blockIdx.y * 256;
    const int NIT = DIN / BK;  // 112

    if (wave < 8) {
        // ================= CONSUMERS =================
        const int wm = wave >> 1, wn = wave & 1;  // 64x64 wave tile
        const int l15 = lane & 15;
        const int kf0 = (lane >> 4) << 3;

        f32x4 acc1[4][4], acc3[4][4];
#pragma unroll
        for (int m = 0; m < 4; ++m)
#pragma unroll
            for (int n = 0; n < 4; ++n) {
                acc1[m][n] = (f32x4)0.0f;
                acc3[m][n] = (f32x4)0.0f;
            }

        __builtin_amdgcn_s_barrier();  // wait for producers' tile-0 staging

        int cur = 0;
        for (int t = 0; t < NIT; ++t) {
#pragma unroll
            for (int ks = 0; ks < 2; ++ks) {
                const int kf = ks * 32 + kf0;
                bf16x8 af[4];
#pragma unroll
                for (int m = 0; m < 4; ++m)
                    af[m] = *(const bf16x8*)&As[cur][swz(wm * 64 + m * 16 + l15, kf)];
#pragma unroll
                for (int n = 0; n < 4; ++n) {
                    const bf16x8 b1f = *(const bf16x8*)&B1s[cur][swz(wn * 64 + n * 16 + l15, kf)];
                    const bf16x8 b3f = *(const bf16x8*)&B3s[cur][swz(wn * 64 + n * 16 + l15, kf)];
                    __builtin_amdgcn_s_setprio(1);
#pragma unroll
                    for (int m = 0; m < 4; ++m)
                        acc1[m][n] = MFMA(af[m], b1f, acc1[m][n], 0, 0, 0);
#pragma unroll
                    for (int m = 0; m < 4; ++m)
                        acc3[m][n] = MFMA(af[m], b3f, acc3[m][n], 0, 0, 0);
                    __builtin_amdgcn_s_setprio(0);
                }
            }
            __builtin_amdgcn_s_barrier();
            cur ^= 1;
        }

        // epilogue: bias + silu*mul -> bf16 g
        float bias1[4], bias3[4];
#pragma unroll
        for (int n = 0; n < 4; ++n) {
            const int f = bn + wn * 64 + n * 16 + l15;
            bias1[n] = b1[e * DINT + f];
            bias3[n] = b3[e * DINT + f];
        }
#pragma unroll
        for (int m = 0; m < 4; ++m)
#pragma unroll
            for (int n = 0; n < 4; ++n) {
                const int f = bn + wn * 64 + n * 16 + l15;
#pragma unroll
                for (int j = 0; j < 4; ++j) {
                    const int t = bm + wm * 64 + m * 16 + ((lane >> 4) << 2) + j;
                    const float h1 = acc1[m][n][j] + bias1[n];
                    const float h3 = acc3[m][n][j] + bias3[n];
                    const float sg = h1 / (1.0f + __expf(-h1));
                    g[(size_t)e * NT * DINT + (size_t)t * DINT + f] =
                        __builtin_bit_cast(unsigned short, (__bf16)(sg * h3));
                }
            }
    } else {
        // ================= PRODUCERS =================
        const int pw = wave - 8;  // 0,1: x halves; 2: w1; 3: w3
        const char* xb = (const char*)x + ((size_t)e * NT * DIN + (size_t)bm * DIN) * 4;
        const char* w1c = (const char*)w1 + ((size_t)e * DINT * DIN + (size_t)bn * DIN) * 4;
        const char* w3c = (const char*)w3 + ((size_t)e * DINT * DIN + (size_t)bn * DIN) * 4;

        const int lrow = lane >> 3;       // 0..7
        const int gcol = (lane & 7) * 8;  // fp32 elems (32B per load pair)
        const int rb = (pw == 1) ? 128 : 0;

        const char* base = (pw < 2) ? xb : (pw == 2 ? w1c : w3c);
        unsigned short* L0;
        unsigned short* L1;
        if (pw < 2) { L0 = &As[0][rb * 64]; L1 = &As[1][rb * 64]; }
        else if (pw == 2) { L0 = B1s[0]; L1 = B1s[1]; }
        else { L0 = B3s[0]; L1 = B3s[1]; }

        // per-lane invariant offsets; pass p adds p*8 rows
        const char* row0 = base + ((size_t)(rb + lrow) * DIN + gcol) * 4;
        const int lidx0 = swz(lrow, gcol);  // + p*8*64 elems per pass (row&7 invariant)

        float4 fa[32];

        // ---- prologue: stage tile 0 -> buf0, prefetch tile 1 ----
#pragma unroll
        for (int p = 0; p < 16; ++p) {
            fa[2 * p] = *(const float4*)(row0 + p * (8 * DIN * 4));
            fa[2 * p + 1] = *(const float4*)(row0 + p * (8 * DIN * 4) + 16);
        }
#pragma unroll
        for (int p = 0; p < 16; ++p)
            *(ushort8v*)&L0[lidx0 + p * 512] = cvt8(fa[2 * p], fa[2 * p + 1]);
#pragma unroll
        for (int p = 0; p < 16; ++p) {
            fa[2 * p] = *(const float4*)(row0 + p * (8 * DIN * 4) + BK * 4);
            fa[2 * p + 1] = *(const float4*)(row0 + p * (8 * DIN * 4) + BK * 4 + 16);
        }
        barrier_lgkm();

        for (int t = 0; t < NIT; ++t) {
            unsigned short* lb = ((t + 1) & 1) ? L1 : L0;
            const int kld = ((t + 2 < NIT) ? (t + 2) : (NIT - 1)) * BK * 4;
            // write tile t+1 (regs landed a tile ago), issue loads for t+2
#pragma unroll
            for (int p = 0; p < 16; ++p) {
                *(ushort8v*)&lb[lidx0 + p * 512] = cvt8(fa[2 * p], fa[2 * p + 1]);
                fa[2 * p] = *(const float4*)(row0 + p * (8 * DIN * 4) + kld);
                fa[2 * p + 1] = *(const float4*)(row0 + p * (8 * DIN * 4) + kld + 16);
            }
            barrier_lgkm();
        }
    }
}

// ---------------- Kernel B: down (R6 version, proven 153 us) ----------------
// BM=256 x BN=128, 512 thr, wave 64x64. grid (56,2,8)=896. dbuf 96 KB.
// 2 phases per K-tile, each 16 MFMA + half the staging.
__global__ __launch_bounds__(512, 2) void ffn_down(
    const unsigned short* __restrict__ g, const float* __restrict__ w2,
    const float* __restrict__ b2, float* __restrict__ out) {
    __shared__ unsigned short As[2][256 * BK];  // 64 KB
    __shared__ unsigned short Bs[2][128 * BK];  // 32 KB

    const int tid = threadIdx.x;
    const int lane = tid & 63;
    const int wave = tid >> 6;
    const int wm = wave >> 1, wn = wave & 1;
    const int e = blockIdx.z;
    const int bn = blockIdx.x * 128;
    const int bm = blockIdx.y * 256;

    const char* gc = (const char*)g + ((size_t)e * NT * DINT + (size_t)bm * DINT) * 2;
    const char* w2c = (const char*)w2 + ((size_t)e * DIN * DINT + (size_t)bn * DINT) * 4;

    const int arow = tid >> 3;          // 0..63
    const int acol = (tid & 7) * 8;     // bf16 elems
    const int brow = tid >> 4;          // 0..31
    const int bcol = (tid & 15) * 4;
    const int swA = swz(arow, acol);    // p-invariant
    const int swB = swz(brow, bcol);

    int go[4], wo[4];
#pragma unroll
    for (int p = 0; p < 4; ++p) {
        go[p] = ((p * 64 + arow) * DINT + acol) * 2;
        wo[p] = ((p * 32 + brow) * DINT + bcol) * 4;
    }

    f32x4 acc[4][4];
#pragma unroll
    for (int m = 0; m < 4; ++m)
#pragma unroll
        for (int n = 0; n < 4; ++n) acc[m][n] = (f32x4)0.0f;

    ushort8v ga[4];
    float4 rb[4];

#pragma unroll
    for (int p = 0; p < 4; ++p) ga[p] = *(const ushort8v*)(gc + go[p]);
#pragma unroll
    for (int p = 0; p < 4; ++p) rb[p] = *(const float4*)(w2c + wo[p]);
#pragma unroll
    for (int p = 0; p < 4; ++p) *(ushort8v*)&As[0][p * 4096 + swA] = ga[p];
#pragma unroll
    for (int p = 0; p < 4; ++p) *(ushort4*)&Bs[0][p * 2048 + swB] = cvt4(rb[p]);
#pragma unroll
    for (int p = 0; p < 4; ++p) ga[p] = *(const ushort8v*)(gc + go[p] + BK * 2);
#pragma unroll
    for (int p = 0; p < 4; ++p) rb[p] = *(const float4*)(w2c + wo[p] + BK * 4);
    barrier_lgkm();

    const int l15 = lane & 15;
    const int kf0 = (lane >> 4) << 3;

    int cur = 0;
    const int NIT = DINT / BK;  // 32
    for (int t = 0; t < NIT; ++t) {
        const int nxt = cur ^ 1;
        const int kld = (t + 2 < NIT) ? (t + 2) * BK : (NIT - 1) * BK;
        const bool stage = (t < NIT - 1);
        bf16x8 af[4], bf[4];

        // ---- Phase 0: ks0 ----
#pragma unroll
        for (int m = 0; m < 4; ++m)
            af[m] = *(const bf16x8*)&As[cur][swz(wm * 64 + m * 16 + l15, kf0)];
#pragma unroll
        for (int n = 0; n < 4; ++n)
            bf[n] = *(const bf16x8*)&Bs[cur][swz(wn * 64 + n * 16 + l15, kf0)];
        if (stage) {
#pragma unroll
            for (int p = 0; p < 4; ++p) *(ushort8v*)&As[nxt][p * 4096 + swA] = ga[p];
#pragma unroll
            for (int p = 0; p < 4; ++p) ga[p] = *(const ushort8v*)(gc + go[p] + kld * 2);
        }
        __builtin_amdgcn_s_setprio(1);
#pragma unroll
        for (int n = 0; n < 4; ++n)
#pragma unroll
            for (int m = 0; m < 4; ++m)
                acc[m][n] = MFMA(af[m], bf[n], acc[m][n], 0, 0, 0);
        __builtin_amdgcn_s_setprio(0);
        __builtin_amdgcn_sched_barrier(0);

        // ---- Phase 1: ks1 ----
#pragma unroll
        for (int m = 0; m < 4; ++m)
            af[m] = *(const bf16x8*)&As[cur][swz(wm * 64 + m * 16 + l15, 32 + kf0)];
#pragma unroll
        for (int n = 0; n < 4; ++n)
            bf[n] = *(const bf16x8*)&Bs[cur][swz(wn * 64 + n * 16 + l15, 32 + kf0)];
        if (stage) {
#pragma unroll
            for (int p = 0; p < 4; ++p) *(ushort4*)&Bs[nxt][p * 2048 + swB] = cvt4(rb[p]);
#pragma unroll
            for (int p = 0; p < 4; ++p) rb[p] = *(const float4*)(w2c + wo[p] + kld * 4);
        }
        __builtin_amdgcn_s_setprio(1);
#pragma unroll
        for (int n = 0; n < 4; ++n)
#pragma unroll
            for (int m = 0; m < 4; ++m)
                acc[m][n] = MFMA(af[m], bf[n], acc[m][n], 0, 0, 0);
        __builtin_amdgcn_s_setprio(0);

        barrier_lgkm();
        cur = nxt;
    }

    float bias[4];
#pragma unroll
    for (int n = 0; n < 4; ++n) {
        const int d = bn + wn * 64 + n * 16 + l15;
        bias[n] = b2[e * DIN + d];
    }
#pragma unroll
    for (int m = 0; m < 4; ++m)
#pragma unroll
        for (int n = 0; n < 4; ++n) {
            const int d = bn + wn * 64 + n * 16 + l15;
#pragma unroll
            for (int j = 0; j < 4; ++j) {
                const int t = bm + wm * 64 + m * 16 + ((lane >> 4) << 2) + j;
                out[(size_t)e * NT * DIN + (size_t)t * DIN + d] = acc[m][n][j] + bias[n];
            }
        }
}

extern "C" void kernel_launch(void* const* d_in, const int* in_sizes, int n_in,
                              void* d_out, int out_size, void* d_ws, size_t ws_size,
                              hipStream_t stream) {
    const float* x = (const float*)d_in[0];
    const float* w1 = (const float*)d_in[1];
    const float* b1 = (const float*)d_in[2];
    const float* w3 = (const float*)d_in[3];
    const float* b3 = (const float*)d_in[4];
    const float* w2 = (const float*)d_in[5];
    const float* b2 = (const float*)d_in[6];
    float* out = (float*)d_out;
    unsigned short* g = (unsigned short*)d_ws;  // [E][T][DINT] bf16

    dim3 gridA(DINT / 128, NT / 256, NE);  // (16, 2, 8) = 256 blocks = 1/CU
    dim3 gridB(DIN / 128, NT / 256, NE);   // (56, 2, 8) = 896 blocks
    ffn_gate_up<<<gridA, dim3(768), 0, stream>>>(x, w1, b1, w3, b3, g);
    ffn_down<<<gridB, dim3(512), 0, stream>>>(g, w2, b2, out);
}